// Round 1
// baseline (1424.462 us; speedup 1.0000x reference)
//
#include <hip/hip_runtime.h>

#define N_NODES 50000
#define N_EDGES 800000
#define EMB 96
#define HID 192
#define BN 64
#define BJ 64
#define KT 32

// ---- scatter: aggr[dst] += h[src] + edge_attr  (one thread = one float4 chunk of one edge)
__global__ __launch_bounds__(256) void scatter_kernel(
    const float4* __restrict__ h4, const float4* __restrict__ ea4,
    const int* __restrict__ src, const int* __restrict__ dst,
    float* __restrict__ aggr)
{
    int idx = blockIdx.x * 256 + threadIdx.x;
    if (idx >= N_EDGES * 24) return;
    int e = idx / 24;
    int c = idx % 24;
    int s = src[e], d = dst[e];
    float4 m = h4[s * 24 + c];
    float4 a = ea4[e * 24 + c];
    m.x += a.x; m.y += a.y; m.z += a.z; m.w += a.w;
    float* o = aggr + d * EMB + c * 4;
    atomicAdd(o + 0, m.x);
    atomicAdd(o + 1, m.y);
    atomicAdd(o + 2, m.z);
    atomicAdd(o + 3, m.w);
}

// ---- layer 1: hidden = relu(aggr @ W1 + b1), tile 64 nodes x 64 cols, 4x4/thread
__global__ __launch_bounds__(256) void mlp1_kernel(
    const float* __restrict__ aggr, const float* __restrict__ W1,
    const float* __restrict__ b1, float* __restrict__ hidden)
{
    __shared__ float sA[BN][EMB + 1];
    __shared__ float sW[EMB][BJ];
    int n0 = blockIdx.x * BN;
    int j0 = blockIdx.y * BJ;
    int t = threadIdx.x;

    for (int i = t; i < BN * (EMB / 4); i += 256) {
        int row = i / (EMB / 4);
        int c   = i % (EMB / 4);
        float4 v = make_float4(0.f, 0.f, 0.f, 0.f);
        if (n0 + row < N_NODES)
            v = ((const float4*)aggr)[(size_t)(n0 + row) * (EMB / 4) + c];
        sA[row][c * 4 + 0] = v.x; sA[row][c * 4 + 1] = v.y;
        sA[row][c * 4 + 2] = v.z; sA[row][c * 4 + 3] = v.w;
    }
    for (int i = t; i < EMB * (BJ / 4); i += 256) {
        int k = i / (BJ / 4);
        int c = i % (BJ / 4);
        float4 v = *(const float4*)(W1 + (size_t)k * HID + j0 + c * 4);
        *(float4*)&sW[k][c * 4] = v;
    }
    __syncthreads();

    int tx = t % 16, ty = t / 16;
    float acc[4][4];
    float4 bv = *(const float4*)(b1 + j0 + tx * 4);
    for (int i = 0; i < 4; ++i) {
        acc[i][0] = bv.x; acc[i][1] = bv.y; acc[i][2] = bv.z; acc[i][3] = bv.w;
    }
    for (int k = 0; k < EMB; ++k) {
        float a0 = sA[ty * 4 + 0][k];
        float a1 = sA[ty * 4 + 1][k];
        float a2 = sA[ty * 4 + 2][k];
        float a3 = sA[ty * 4 + 3][k];
        float4 w = *(float4*)&sW[k][tx * 4];
        acc[0][0] += a0 * w.x; acc[0][1] += a0 * w.y; acc[0][2] += a0 * w.z; acc[0][3] += a0 * w.w;
        acc[1][0] += a1 * w.x; acc[1][1] += a1 * w.y; acc[1][2] += a1 * w.z; acc[1][3] += a1 * w.w;
        acc[2][0] += a2 * w.x; acc[2][1] += a2 * w.y; acc[2][2] += a2 * w.z; acc[2][3] += a2 * w.w;
        acc[3][0] += a3 * w.x; acc[3][1] += a3 * w.y; acc[3][2] += a3 * w.z; acc[3][3] += a3 * w.w;
    }
    for (int i = 0; i < 4; ++i) {
        int n = n0 + ty * 4 + i;
        if (n < N_NODES) {
            float4 o;
            o.x = fmaxf(acc[i][0], 0.f);
            o.y = fmaxf(acc[i][1], 0.f);
            o.z = fmaxf(acc[i][2], 0.f);
            o.w = fmaxf(acc[i][3], 0.f);
            ((float4*)hidden)[(size_t)n * (HID / 4) + (j0 / 4) + tx] = o;
        }
    }
}

// ---- layer 2 + residual: out = (1+eps)*h + hidden @ W2 + b2, tile 64 nodes x 96 cols
__global__ __launch_bounds__(384) void mlp2_kernel(
    const float* __restrict__ hidden, const float* __restrict__ W2,
    const float* __restrict__ b2, const float* __restrict__ h,
    const float* __restrict__ eps, float* __restrict__ out)
{
    __shared__ float sH[BN][KT + 1];
    __shared__ float sW[KT][EMB];
    int n0 = blockIdx.x * BN;
    int t = threadIdx.x;
    int tx = t % 24, ty = t / 24;  // ty in [0,16)

    float acc[4][4];
    float4 bv = *(const float4*)(b2 + tx * 4);
    for (int i = 0; i < 4; ++i) {
        acc[i][0] = bv.x; acc[i][1] = bv.y; acc[i][2] = bv.z; acc[i][3] = bv.w;
    }

    for (int kt = 0; kt < HID; kt += KT) {
        __syncthreads();
        for (int i = t; i < BN * (KT / 4); i += 384) {
            int row = i / (KT / 4);
            int c   = i % (KT / 4);
            float4 v = make_float4(0.f, 0.f, 0.f, 0.f);
            if (n0 + row < N_NODES)
                v = ((const float4*)hidden)[(size_t)(n0 + row) * (HID / 4) + kt / 4 + c];
            sH[row][c * 4 + 0] = v.x; sH[row][c * 4 + 1] = v.y;
            sH[row][c * 4 + 2] = v.z; sH[row][c * 4 + 3] = v.w;
        }
        for (int i = t; i < KT * (EMB / 4); i += 384) {
            int kr = i / (EMB / 4);
            int c  = i % (EMB / 4);
            *(float4*)&sW[kr][c * 4] = *(const float4*)(W2 + (size_t)(kt + kr) * EMB + c * 4);
        }
        __syncthreads();
        for (int k = 0; k < KT; ++k) {
            float a0 = sH[ty * 4 + 0][k];
            float a1 = sH[ty * 4 + 1][k];
            float a2 = sH[ty * 4 + 2][k];
            float a3 = sH[ty * 4 + 3][k];
            float4 w = *(float4*)&sW[k][tx * 4];
            acc[0][0] += a0 * w.x; acc[0][1] += a0 * w.y; acc[0][2] += a0 * w.z; acc[0][3] += a0 * w.w;
            acc[1][0] += a1 * w.x; acc[1][1] += a1 * w.y; acc[1][2] += a1 * w.z; acc[1][3] += a1 * w.w;
            acc[2][0] += a2 * w.x; acc[2][1] += a2 * w.y; acc[2][2] += a2 * w.z; acc[2][3] += a2 * w.w;
            acc[3][0] += a3 * w.x; acc[3][1] += a3 * w.y; acc[3][2] += a3 * w.z; acc[3][3] += a3 * w.w;
        }
    }

    float scale = 1.f + eps[0];
    for (int i = 0; i < 4; ++i) {
        int n = n0 + ty * 4 + i;
        if (n < N_NODES) {
            float4 hv = ((const float4*)h)[(size_t)n * (EMB / 4) + tx];
            float4 o;
            o.x = acc[i][0] + scale * hv.x;
            o.y = acc[i][1] + scale * hv.y;
            o.z = acc[i][2] + scale * hv.z;
            o.w = acc[i][3] + scale * hv.w;
            ((float4*)out)[(size_t)n * (EMB / 4) + tx] = o;
        }
    }
}

extern "C" void kernel_launch(void* const* d_in, const int* in_sizes, int n_in,
                              void* d_out, int out_size, void* d_ws, size_t ws_size,
                              hipStream_t stream) {
    const float* h         = (const float*)d_in[0];
    const float* edge_attr = (const float*)d_in[1];
    const int*   src       = (const int*)d_in[2];
    const int*   dst       = (const int*)d_in[3];
    const float* W1        = (const float*)d_in[4];
    const float* b1        = (const float*)d_in[5];
    const float* W2        = (const float*)d_in[6];
    const float* b2        = (const float*)d_in[7];
    const float* eps       = (const float*)d_in[8];
    float* out    = (float*)d_out;
    float* aggr   = (float*)d_ws;                        // 50000*96 f32 = 19.2 MB
    float* hidden = aggr + (size_t)N_NODES * EMB;        // 50000*192 f32 = 38.4 MB

    hipMemsetAsync(aggr, 0, (size_t)N_NODES * EMB * sizeof(float), stream);

    int scatter_blocks = (N_EDGES * 24 + 255) / 256;
    scatter_kernel<<<scatter_blocks, 256, 0, stream>>>(
        (const float4*)h, (const float4*)edge_attr, src, dst, aggr);

    dim3 g1((N_NODES + BN - 1) / BN, HID / BJ);
    mlp1_kernel<<<g1, 256, 0, stream>>>(aggr, W1, b1, hidden);

    int g2 = (N_NODES + BN - 1) / BN;
    mlp2_kernel<<<g2, 384, 0, stream>>>(hidden, W2, b2, h, eps, out);
}

// Round 2
// 668.249 us; speedup vs baseline: 2.1316x; 2.1316x over previous
//
#include <hip/hip_runtime.h>

#define N_NODES 50000
#define N_EDGES 800000
#define EMB 96
#define HID 192
#define BN 64
#define BJ 64
#define KT 32

// ---- CSR build step 1: histogram of dst
__global__ __launch_bounds__(256) void hist_kernel(
    const int* __restrict__ dst, int* __restrict__ counts)
{
    int e = blockIdx.x * 256 + threadIdx.x;
    if (e < N_EDGES) atomicAdd(&counts[dst[e]], 1);
}

// ---- CSR build step 2: exclusive scan of counts (single workgroup, 1024 thr)
__global__ __launch_bounds__(1024) void scan_kernel(
    const int* __restrict__ counts, int* __restrict__ offsets)
{
    __shared__ int wave_sums[16];
    int t = threadIdx.x;
    int lane = t & 63, wave = t >> 6;
    int running = 0;
    for (int base = 0; base < N_NODES; base += 1024) {
        int v = (base + t < N_NODES) ? counts[base + t] : 0;
        int x = v;
        #pragma unroll
        for (int d = 1; d < 64; d <<= 1) {
            int y = __shfl_up(x, d);
            if (lane >= d) x += y;
        }
        if (lane == 63) wave_sums[wave] = x;
        __syncthreads();
        if (t < 16) {
            int s = wave_sums[t];
            #pragma unroll
            for (int d = 1; d < 16; d <<= 1) {
                int y = __shfl_up(s, d);
                if (t >= d) s += y;
            }
            wave_sums[t] = s;
        }
        __syncthreads();
        int woff = wave ? wave_sums[wave - 1] : 0;
        if (base + t < N_NODES) offsets[base + t] = running + woff + x - v;
        int total = wave_sums[15];
        __syncthreads();
        running += total;
    }
    if (t == 0) offsets[N_NODES] = running;
}

// ---- CSR build step 3: fill buckets with (edge_id, src) pairs
__global__ __launch_bounds__(256) void fill_kernel(
    const int* __restrict__ src, const int* __restrict__ dst,
    const int* __restrict__ offsets, int* __restrict__ cursor,
    int2* __restrict__ pairs)
{
    int e = blockIdx.x * 256 + threadIdx.x;
    if (e < N_EDGES) {
        int d = dst[e];
        int pos = offsets[d] + atomicAdd(&cursor[d], 1);
        pairs[pos] = make_int2(e, src[e]);
    }
}

// ---- gather-reduce: aggr[n] = sum over edges e with dst==n of (h[src_e]+ea_e)
// 24 lanes per node (one float4 each), 8 nodes per 192-thread block
__global__ __launch_bounds__(192) void gather_kernel(
    const float4* __restrict__ h4, const float4* __restrict__ ea4,
    const int* __restrict__ offsets, const int2* __restrict__ pairs,
    float4* __restrict__ aggr4)
{
    int n = blockIdx.x * 8 + threadIdx.x / 24;
    int c = threadIdx.x % 24;
    if (n >= N_NODES) return;
    int beg = offsets[n], end = offsets[n + 1];
    float4 acc = make_float4(0.f, 0.f, 0.f, 0.f);
    int i = beg;
    int2 p = (i < end) ? pairs[i] : make_int2(0, 0);
    while (i < end) {
        int2 cur = p;
        ++i;
        if (i < end) p = pairs[i];          // prefetch next edge descriptor
        float4 a = ea4[(size_t)cur.x * 24 + c];
        float4 b = h4[(size_t)cur.y * 24 + c];
        acc.x += a.x + b.x;
        acc.y += a.y + b.y;
        acc.z += a.z + b.z;
        acc.w += a.w + b.w;
    }
    aggr4[(size_t)n * 24 + c] = acc;
}

// ---- layer 1: hidden = relu(aggr @ W1 + b1), tile 64 nodes x 64 cols, 4x4/thread
__global__ __launch_bounds__(256) void mlp1_kernel(
    const float* __restrict__ aggr, const float* __restrict__ W1,
    const float* __restrict__ b1, float* __restrict__ hidden)
{
    __shared__ float sA[BN][EMB + 1];
    __shared__ float sW[EMB][BJ];
    int n0 = blockIdx.x * BN;
    int j0 = blockIdx.y * BJ;
    int t = threadIdx.x;

    for (int i = t; i < BN * (EMB / 4); i += 256) {
        int row = i / (EMB / 4);
        int c   = i % (EMB / 4);
        float4 v = make_float4(0.f, 0.f, 0.f, 0.f);
        if (n0 + row < N_NODES)
            v = ((const float4*)aggr)[(size_t)(n0 + row) * (EMB / 4) + c];
        sA[row][c * 4 + 0] = v.x; sA[row][c * 4 + 1] = v.y;
        sA[row][c * 4 + 2] = v.z; sA[row][c * 4 + 3] = v.w;
    }
    for (int i = t; i < EMB * (BJ / 4); i += 256) {
        int k = i / (BJ / 4);
        int c = i % (BJ / 4);
        float4 v = *(const float4*)(W1 + (size_t)k * HID + j0 + c * 4);
        *(float4*)&sW[k][c * 4] = v;
    }
    __syncthreads();

    int tx = t % 16, ty = t / 16;
    float acc[4][4];
    float4 bv = *(const float4*)(b1 + j0 + tx * 4);
    for (int i = 0; i < 4; ++i) {
        acc[i][0] = bv.x; acc[i][1] = bv.y; acc[i][2] = bv.z; acc[i][3] = bv.w;
    }
    for (int k = 0; k < EMB; ++k) {
        float a0 = sA[ty * 4 + 0][k];
        float a1 = sA[ty * 4 + 1][k];
        float a2 = sA[ty * 4 + 2][k];
        float a3 = sA[ty * 4 + 3][k];
        float4 w = *(float4*)&sW[k][tx * 4];
        acc[0][0] += a0 * w.x; acc[0][1] += a0 * w.y; acc[0][2] += a0 * w.z; acc[0][3] += a0 * w.w;
        acc[1][0] += a1 * w.x; acc[1][1] += a1 * w.y; acc[1][2] += a1 * w.z; acc[1][3] += a1 * w.w;
        acc[2][0] += a2 * w.x; acc[2][1] += a2 * w.y; acc[2][2] += a2 * w.z; acc[2][3] += a2 * w.w;
        acc[3][0] += a3 * w.x; acc[3][1] += a3 * w.y; acc[3][2] += a3 * w.z; acc[3][3] += a3 * w.w;
    }
    for (int i = 0; i < 4; ++i) {
        int n = n0 + ty * 4 + i;
        if (n < N_NODES) {
            float4 o;
            o.x = fmaxf(acc[i][0], 0.f);
            o.y = fmaxf(acc[i][1], 0.f);
            o.z = fmaxf(acc[i][2], 0.f);
            o.w = fmaxf(acc[i][3], 0.f);
            ((float4*)hidden)[(size_t)n * (HID / 4) + (j0 / 4) + tx] = o;
        }
    }
}

// ---- layer 2 + residual: out = (1+eps)*h + hidden @ W2 + b2
__global__ __launch_bounds__(384) void mlp2_kernel(
    const float* __restrict__ hidden, const float* __restrict__ W2,
    const float* __restrict__ b2, const float* __restrict__ h,
    const float* __restrict__ eps, float* __restrict__ out)
{
    __shared__ float sH[BN][KT + 1];
    __shared__ float sW[KT][EMB];
    int n0 = blockIdx.x * BN;
    int t = threadIdx.x;
    int tx = t % 24, ty = t / 24;  // ty in [0,16)

    float acc[4][4];
    float4 bv = *(const float4*)(b2 + tx * 4);
    for (int i = 0; i < 4; ++i) {
        acc[i][0] = bv.x; acc[i][1] = bv.y; acc[i][2] = bv.z; acc[i][3] = bv.w;
    }

    for (int kt = 0; kt < HID; kt += KT) {
        __syncthreads();
        for (int i = t; i < BN * (KT / 4); i += 384) {
            int row = i / (KT / 4);
            int c   = i % (KT / 4);
            float4 v = make_float4(0.f, 0.f, 0.f, 0.f);
            if (n0 + row < N_NODES)
                v = ((const float4*)hidden)[(size_t)(n0 + row) * (HID / 4) + kt / 4 + c];
            sH[row][c * 4 + 0] = v.x; sH[row][c * 4 + 1] = v.y;
            sH[row][c * 4 + 2] = v.z; sH[row][c * 4 + 3] = v.w;
        }
        for (int i = t; i < KT * (EMB / 4); i += 384) {
            int kr = i / (EMB / 4);
            int c  = i % (EMB / 4);
            *(float4*)&sW[kr][c * 4] = *(const float4*)(W2 + (size_t)(kt + kr) * EMB + c * 4);
        }
        __syncthreads();
        for (int k = 0; k < KT; ++k) {
            float a0 = sH[ty * 4 + 0][k];
            float a1 = sH[ty * 4 + 1][k];
            float a2 = sH[ty * 4 + 2][k];
            float a3 = sH[ty * 4 + 3][k];
            float4 w = *(float4*)&sW[k][tx * 4];
            acc[0][0] += a0 * w.x; acc[0][1] += a0 * w.y; acc[0][2] += a0 * w.z; acc[0][3] += a0 * w.w;
            acc[1][0] += a1 * w.x; acc[1][1] += a1 * w.y; acc[1][2] += a1 * w.z; acc[1][3] += a1 * w.w;
            acc[2][0] += a2 * w.x; acc[2][1] += a2 * w.y; acc[2][2] += a2 * w.z; acc[2][3] += a2 * w.w;
            acc[3][0] += a3 * w.x; acc[3][1] += a3 * w.y; acc[3][2] += a3 * w.z; acc[3][3] += a3 * w.w;
        }
    }

    float scale = 1.f + eps[0];
    for (int i = 0; i < 4; ++i) {
        int n = n0 + ty * 4 + i;
        if (n < N_NODES) {
            float4 hv = ((const float4*)h)[(size_t)n * (EMB / 4) + tx];
            float4 o;
            o.x = acc[i][0] + scale * hv.x;
            o.y = acc[i][1] + scale * hv.y;
            o.z = acc[i][2] + scale * hv.z;
            o.w = acc[i][3] + scale * hv.w;
            ((float4*)out)[(size_t)n * (EMB / 4) + tx] = o;
        }
    }
}

extern "C" void kernel_launch(void* const* d_in, const int* in_sizes, int n_in,
                              void* d_out, int out_size, void* d_ws, size_t ws_size,
                              hipStream_t stream) {
    const float* h         = (const float*)d_in[0];
    const float* edge_attr = (const float*)d_in[1];
    const int*   src       = (const int*)d_in[2];
    const int*   dst       = (const int*)d_in[3];
    const float* W1        = (const float*)d_in[4];
    const float* b1        = (const float*)d_in[5];
    const float* W2        = (const float*)d_in[6];
    const float* b2        = (const float*)d_in[7];
    const float* eps       = (const float*)d_in[8];
    float* out    = (float*)d_out;

    // workspace layout
    float* aggr    = (float*)d_ws;                         // 50000*96  f32 = 19.2 MB
    float* hidden  = aggr + (size_t)N_NODES * EMB;         // 50000*192 f32 = 38.4 MB
    int2*  pairs   = (int2*)(hidden + (size_t)N_NODES * HID); // 800000 int2 = 6.4 MB
    int*   offsets = (int*)(pairs + N_EDGES);              // 50001 ints
    int*   counts  = offsets + N_NODES + 1;                // 50000 ints
    int*   cursor  = counts + N_NODES;                     // 50000 ints

    // zero counts + cursor (adjacent)
    hipMemsetAsync(counts, 0, (size_t)2 * N_NODES * sizeof(int), stream);

    hist_kernel<<<(N_EDGES + 255) / 256, 256, 0, stream>>>(dst, counts);
    scan_kernel<<<1, 1024, 0, stream>>>(counts, offsets);
    fill_kernel<<<(N_EDGES + 255) / 256, 256, 0, stream>>>(src, dst, offsets, cursor, pairs);
    gather_kernel<<<(N_NODES + 7) / 8, 192, 0, stream>>>(
        (const float4*)h, (const float4*)edge_attr, offsets, pairs, (float4*)aggr);

    dim3 g1((N_NODES + BN - 1) / BN, HID / BJ);
    mlp1_kernel<<<g1, 256, 0, stream>>>(aggr, W1, b1, hidden);

    int g2 = (N_NODES + BN - 1) / BN;
    mlp2_kernel<<<g2, 384, 0, stream>>>(hidden, W2, b2, h, eps, out);
}

// Round 3
// 615.834 us; speedup vs baseline: 2.3131x; 1.0851x over previous
//
#include <hip/hip_runtime.h>

#define N_NODES 50000
#define N_EDGES 800000
#define EMB 96
#define HID 192

typedef __attribute__((ext_vector_type(8))) short short8;
typedef __attribute__((ext_vector_type(4))) float f32x4;
typedef __attribute__((ext_vector_type(4))) unsigned short ushort4v;

static __device__ __forceinline__ unsigned short f2bf(float f) {
    union { float f; unsigned int u; } v; v.f = f;
    unsigned int u = v.u;
    return (unsigned short)((u + 0x7FFFu + ((u >> 16) & 1u)) >> 16);
}

// ---- CSR build step 1: histogram of dst
__global__ __launch_bounds__(256) void hist_kernel(
    const int* __restrict__ dst, int* __restrict__ counts)
{
    int e = blockIdx.x * 256 + threadIdx.x;
    if (e < N_EDGES) atomicAdd(&counts[dst[e]], 1);
}

// ---- CSR build step 2: exclusive scan of counts (single workgroup, 1024 thr)
__global__ __launch_bounds__(1024) void scan_kernel(
    const int* __restrict__ counts, int* __restrict__ offsets)
{
    __shared__ int wave_sums[16];
    int t = threadIdx.x;
    int lane = t & 63, wave = t >> 6;
    int running = 0;
    for (int base = 0; base < N_NODES; base += 1024) {
        int v = (base + t < N_NODES) ? counts[base + t] : 0;
        int x = v;
        #pragma unroll
        for (int d = 1; d < 64; d <<= 1) {
            int y = __shfl_up(x, d);
            if (lane >= d) x += y;
        }
        if (lane == 63) wave_sums[wave] = x;
        __syncthreads();
        if (t < 16) {
            int s = wave_sums[t];
            #pragma unroll
            for (int d = 1; d < 16; d <<= 1) {
                int y = __shfl_up(s, d);
                if (t >= d) s += y;
            }
            wave_sums[t] = s;
        }
        __syncthreads();
        int woff = wave ? wave_sums[wave - 1] : 0;
        if (base + t < N_NODES) offsets[base + t] = running + woff + x - v;
        int total = wave_sums[15];
        __syncthreads();
        running += total;
    }
    if (t == 0) offsets[N_NODES] = running;
}

// ---- CSR build step 3: fill buckets with (edge_id, src) pairs
__global__ __launch_bounds__(256) void fill_kernel(
    const int* __restrict__ src, const int* __restrict__ dst,
    const int* __restrict__ offsets, int* __restrict__ cursor,
    int2* __restrict__ pairs)
{
    int e = blockIdx.x * 256 + threadIdx.x;
    if (e < N_EDGES) {
        int d = dst[e];
        int pos = offsets[d] + atomicAdd(&cursor[d], 1);
        pairs[pos] = make_int2(e, src[e]);
    }
}

// ---- weight transpose + bf16 convert: W1t[n][k]=W1[k][n], W2t[n][k]=W2[k][n]
__global__ __launch_bounds__(256) void conv_kernel(
    const float* __restrict__ W1, const float* __restrict__ W2,
    unsigned short* __restrict__ W1t, unsigned short* __restrict__ W2t)
{
    int i = blockIdx.x * 256 + threadIdx.x;
    if (i < EMB * HID) {                 // W1t: [HID][EMB]
        int n = i / EMB, k = i % EMB;
        W1t[i] = f2bf(W1[(size_t)k * HID + n]);
    } else if (i < 2 * EMB * HID) {      // W2t: [EMB][HID]
        int j = i - EMB * HID;
        int n = j / HID, k = j % HID;
        W2t[j] = f2bf(W2[(size_t)k * EMB + n]);
    }
}

// ---- gather-reduce: aggr_bf[n] = bf16( sum_e (h[src_e]+ea_e) ), 24 lanes/node
__global__ __launch_bounds__(192) void gather_kernel(
    const float4* __restrict__ h4, const float4* __restrict__ ea4,
    const int* __restrict__ offsets, const int2* __restrict__ pairs,
    unsigned short* __restrict__ aggr_bf)
{
    int n = blockIdx.x * 8 + threadIdx.x / 24;
    int c = threadIdx.x % 24;
    if (n >= N_NODES) return;
    int beg = offsets[n], end = offsets[n + 1];
    float4 acc = make_float4(0.f, 0.f, 0.f, 0.f);
    int i = beg;
    int2 p = (i < end) ? pairs[i] : make_int2(0, 0);
    while (i < end) {
        int2 cur = p;
        ++i;
        if (i < end) p = pairs[i];
        float4 a = ea4[(size_t)cur.x * 24 + c];
        float4 b = h4[(size_t)cur.y * 24 + c];
        acc.x += a.x + b.x;
        acc.y += a.y + b.y;
        acc.z += a.z + b.z;
        acc.w += a.w + b.w;
    }
    ushort4v o;
    o.x = f2bf(acc.x); o.y = f2bf(acc.y); o.z = f2bf(acc.z); o.w = f2bf(acc.w);
    *(ushort4v*)(aggr_bf + (size_t)n * EMB + c * 4) = o;
}

// ---- layer 1 MFMA: hidden_bf = bf16(relu(aggr @ W1 + b1))
// wave = 16 rows x 192 cols; W1t staged in LDS [192][96] pad-stride 104
__global__ __launch_bounds__(256) void mlp1_mfma(
    const unsigned short* __restrict__ aggr_bf,
    const unsigned short* __restrict__ W1t,
    const float* __restrict__ b1,
    unsigned short* __restrict__ hidden_bf)
{
    __shared__ unsigned short sW[HID * 104];
    int t = threadIdx.x;
    const unsigned int* srcp = (const unsigned int*)W1t;
    for (int i = t; i < HID * (EMB / 2); i += 256) {
        int n = i / (EMB / 2), c = i % (EMB / 2);
        *(unsigned int*)&sW[n * 104 + c * 2] = srcp[(size_t)n * (EMB / 2) + c];
    }
    __syncthreads();
    int wave = t >> 6, lane = t & 63;
    int m0 = (blockIdx.x * 4 + wave) * 16;
    if (m0 >= N_NODES) return;
    int quad = lane >> 4, col = lane & 15;
    f32x4 acc[12];
    #pragma unroll
    for (int c = 0; c < 12; ++c) acc[c] = (f32x4){0.f, 0.f, 0.f, 0.f};
    int m = m0 + col;
    #pragma unroll
    for (int ks = 0; ks < 3; ++ks) {
        short8 af = *(const short8*)(aggr_bf + (size_t)m * EMB + ks * 32 + quad * 8);
        #pragma unroll
        for (int c = 0; c < 12; ++c) {
            short8 bf = *(const short8*)(sW + (c * 16 + col) * 104 + ks * 32 + quad * 8);
            acc[c] = __builtin_amdgcn_mfma_f32_16x16x32_bf16(af, bf, acc[c], 0, 0, 0);
        }
    }
    #pragma unroll
    for (int c = 0; c < 12; ++c) {
        float bias = b1[c * 16 + col];
        #pragma unroll
        for (int r = 0; r < 4; ++r) {
            int row = m0 + quad * 4 + r;
            float v = fmaxf(acc[c][r] + bias, 0.f);
            hidden_bf[(size_t)row * HID + c * 16 + col] = f2bf(v);
        }
    }
}

// ---- layer 2 MFMA + residual: out = (1+eps)*h + hidden @ W2 + b2
// wave = 16 rows x 96 cols; W2t staged in LDS [96][192] pad-stride 200
__global__ __launch_bounds__(256) void mlp2_mfma(
    const unsigned short* __restrict__ hidden_bf,
    const unsigned short* __restrict__ W2t,
    const float* __restrict__ b2,
    const float* __restrict__ h,
    const float* __restrict__ eps,
    float* __restrict__ out)
{
    __shared__ unsigned short sW[EMB * 200];
    int t = threadIdx.x;
    const unsigned int* srcp = (const unsigned int*)W2t;
    for (int i = t; i < EMB * (HID / 2); i += 256) {
        int n = i / (HID / 2), c = i % (HID / 2);
        *(unsigned int*)&sW[n * 200 + c * 2] = srcp[(size_t)n * (HID / 2) + c];
    }
    __syncthreads();
    int wave = t >> 6, lane = t & 63;
    int m0 = (blockIdx.x * 4 + wave) * 16;
    if (m0 >= N_NODES) return;
    int quad = lane >> 4, col = lane & 15;
    f32x4 acc[6];
    #pragma unroll
    for (int c = 0; c < 6; ++c) acc[c] = (f32x4){0.f, 0.f, 0.f, 0.f};
    int m = m0 + col;
    #pragma unroll
    for (int ks = 0; ks < 6; ++ks) {
        short8 af = *(const short8*)(hidden_bf + (size_t)m * HID + ks * 32 + quad * 8);
        #pragma unroll
        for (int c = 0; c < 6; ++c) {
            short8 bf = *(const short8*)(sW + (c * 16 + col) * 200 + ks * 32 + quad * 8);
            acc[c] = __builtin_amdgcn_mfma_f32_16x16x32_bf16(af, bf, acc[c], 0, 0, 0);
        }
    }
    float s = 1.f + eps[0];
    #pragma unroll
    for (int c = 0; c < 6; ++c) {
        float bias = b2[c * 16 + col];
        #pragma unroll
        for (int r = 0; r < 4; ++r) {
            int row = m0 + quad * 4 + r;
            size_t idx = (size_t)row * EMB + c * 16 + col;
            out[idx] = acc[c][r] + bias + s * h[idx];
        }
    }
}

extern "C" void kernel_launch(void* const* d_in, const int* in_sizes, int n_in,
                              void* d_out, int out_size, void* d_ws, size_t ws_size,
                              hipStream_t stream) {
    const float* h         = (const float*)d_in[0];
    const float* edge_attr = (const float*)d_in[1];
    const int*   src       = (const int*)d_in[2];
    const int*   dst       = (const int*)d_in[3];
    const float* W1        = (const float*)d_in[4];
    const float* b1        = (const float*)d_in[5];
    const float* W2        = (const float*)d_in[6];
    const float* b2        = (const float*)d_in[7];
    const float* eps       = (const float*)d_in[8];
    float* out = (float*)d_out;

    unsigned char* wsp = (unsigned char*)d_ws;
    unsigned short* aggr_bf   = (unsigned short*)wsp; wsp += (size_t)N_NODES * EMB * 2;
    unsigned short* hidden_bf = (unsigned short*)wsp; wsp += (size_t)N_NODES * HID * 2;
    unsigned short* W1t       = (unsigned short*)wsp; wsp += (size_t)EMB * HID * 2;
    unsigned short* W2t       = (unsigned short*)wsp; wsp += (size_t)EMB * HID * 2;
    int2* pairs   = (int2*)wsp; wsp += (size_t)N_EDGES * sizeof(int2);
    int*  offsets = (int*)wsp;  wsp += (size_t)(N_NODES + 1) * sizeof(int);
    int*  counts  = (int*)wsp;  wsp += (size_t)N_NODES * sizeof(int);
    int*  cursor  = (int*)wsp;

    hipMemsetAsync(counts, 0, (size_t)2 * N_NODES * sizeof(int), stream);

    hist_kernel<<<(N_EDGES + 255) / 256, 256, 0, stream>>>(dst, counts);
    scan_kernel<<<1, 1024, 0, stream>>>(counts, offsets);
    fill_kernel<<<(N_EDGES + 255) / 256, 256, 0, stream>>>(src, dst, offsets, cursor, pairs);
    conv_kernel<<<(2 * EMB * HID + 255) / 256, 256, 0, stream>>>(W1, W2, W1t, W2t);
    gather_kernel<<<(N_NODES + 7) / 8, 192, 0, stream>>>(
        (const float4*)h, (const float4*)edge_attr, offsets, pairs, aggr_bf);

    mlp1_mfma<<<(N_NODES / 16 + 3) / 4, 256, 0, stream>>>(aggr_bf, W1t, b1, hidden_bf);
    mlp2_mfma<<<(N_NODES / 16 + 3) / 4, 256, 0, stream>>>(hidden_bf, W2t, b2, h, eps, out);
}